// Round 6
// baseline (7370.872 us; speedup 1.0000x reference)
//
#include <hip/hip_runtime.h>
#include <stdint.h>

#define B_ 64
#define T_ 512
#define I_ 256
#define H_ 512
#define G0_ 128
#define G1_ 128
#define NTHR_ 512
#define D_ 8   // ring depth (power of 2)

typedef __attribute__((ext_vector_type(8))) short short8;
typedef __attribute__((ext_vector_type(4))) float float4v;
typedef __attribute__((ext_vector_type(4))) unsigned int uint4v;

static_assert(sizeof(short8) == 16, "");
static_assert(sizeof(uint4v) == 16, "");

// ---- bf16 helpers (round-to-nearest-even) ----
__device__ __forceinline__ unsigned short f2bf(float x) {
  union { float f; uint32_t u; } v; v.f = x;
  uint32_t r = v.u + 0x7FFFu + ((v.u >> 16) & 1u);
  return (unsigned short)(r >> 16);
}
__device__ __forceinline__ float bf2f(unsigned short h) {
  union { uint32_t u; float f; } v; v.u = ((uint32_t)h) << 16; return v.f;
}
__device__ __forceinline__ void splitHL(float x, unsigned short& hi, unsigned short& lo) {
  hi = f2bf(x);
  lo = f2bf(x - bf2f(hi));   // x - hi is exact in fp32
}

// ring element offset (u32 units). fragment layout: [slot][bg][ktile][lane][j]
// each lane's 8 u32 words are CONTIGUOUS (lane*8): word j at p[j], j=0..7.
__device__ __forceinline__ size_t roff(int slot, int bg, int ht, int lane) {
  return ((size_t)((slot * 4 + bg) * 16 + ht)) * 512 + (size_t)lane * 8;
}

__device__ __forceinline__ void unpack8(uint4v w0, uint4v w1, short8& hi, short8& lo) {
  #pragma unroll
  for (int j = 0; j < 4; ++j) {
    hi[j]     = (short)(w0[j] >> 16); lo[j]     = (short)(w0[j] & 0xffffu);
    hi[j + 4] = (short)(w1[j] >> 16); lo[j + 4] = (short)(w1[j] & 0xffffu);
  }
}

#define MFMA16(A, Bv, C) __builtin_amdgcn_mfma_f32_16x16x32_bf16(A, Bv, C, 0, 0, 0)

// counted wait on our asm-issued vmem + scheduling fence (rule #18)
#define WAITV(n) do { \
    asm volatile("s_waitcnt vmcnt(" #n ")" ::: "memory"); \
    __builtin_amdgcn_sched_barrier(0); \
  } while (0)

// ---- single-lane pollers on aggregated done-counters (4 parts per layer) ----
__device__ __forceinline__ void poll2(const uint32_t* da, int ta,
                                      const uint32_t* db, int tb) {
  for (int it = 0; it < 3000000; ++it) {
    uint4v a, b;
    asm volatile("global_load_dwordx4 %0, %2, off sc0 sc1\n\t"
                 "global_load_dwordx4 %1, %3, off sc0 sc1\n\t"
                 "s_waitcnt vmcnt(0)"
                 : "=&v"(a), "=&v"(b) : "v"(da), "v"(db) : "memory");
    int ca = (int)(a[0] + a[1] + a[2] + a[3]);
    int cb = (int)(b[0] + b[1] + b[2] + b[3]);
    if (ca >= ta && cb >= tb) return;
    if (ta - ca > 1024 || tb - cb > 1024) __builtin_amdgcn_s_sleep(8);
  }
}
__device__ __forceinline__ void poll1(const uint32_t* da, int ta) {
  for (int it = 0; it < 3000000; ++it) {
    uint4v a;
    asm volatile("global_load_dwordx4 %0, %1, off sc0 sc1\n\t"
                 "s_waitcnt vmcnt(0)"
                 : "=&v"(a) : "v"(da) : "memory");
    if ((int)(a[0] + a[1] + a[2] + a[3]) >= ta) return;
    if (ta - (int)(a[0] + a[1] + a[2] + a[3]) > 1024) __builtin_amdgcn_s_sleep(8);
  }
}

// One LSTM layer, persistent across all T steps.
// Block 'a' owns h-columns [4a, 4a+4) -> 16 gate columns (4 gates x 4 cols).
// K space: [0,K1)=inp (x or h0), [K1,K1+512)=h_rec.
// MFMA frag conventions: k(q,j) = 4q + (j&3) + 16*(j>>2), q = lane>>4
//   A: row m = lane&15, B: col = lane&15
//   C/D: col = lane&15, row = 4*(lane>>4) + i   (m89-verified)
//
// Protocol: writer stores h frags sc0 sc1 (write-through to MALL) -> per-wave
// vmcnt(0) -> lane0 atomicAdd(done[layer][bg]). Readers: ONE lane polls the
// 4-part counters; ring reads are sc0 (L1-bypass, L2-CACHED -> XCD-wide
// sharing). Epoch hygiene: first block per XCD to advance xcd_ep does ONE
// buffer_inv sc1 per step; all fills are flag-gated so refills are always
// the correct epoch; backpressure keeps slot epochs non-overlapping.
template <int LAYER>
__device__ void run_layer(
    int a,
    const float* __restrict__ x,
    const float* __restrict__ Wxp, const float* __restrict__ bxp,
    const float* __restrict__ Whp,
    uint32_t* done, uint32_t* xcd_ep,
    uint32_t* ring0, uint32_t* ring1,
    float* h1f,
    unsigned short* Wsh, float* red)
{
  constexpr int K1 = LAYER ? H_ : I_;
  constexpr int NT = (K1 + H_) / 32;   // 24 (L0) or 32 (L1) K-tiles
  constexpr int NTT = NT / 2;          // 12 or 16 tiles per k-half wavegroup
  const int tid = threadIdx.x;
  const int lane = tid & 63;
  const int wid = tid >> 6;     // 0..7
  const int bg = wid & 3;       // batch group (16 batches)
  const int kh = wid >> 2;      // K-half (parity of tile)
  const int qq = lane >> 4;
  const int cc = lane & 15;     // A-row / gate column within block
  const int brow = bg * 16 + cc;

  uint32_t xcd = 0;
  asm volatile("s_getreg_b32 %0, hwreg(HW_REG_XCC_ID)" : "=s"(xcd));

  // ---- stage weight slice: pass0 = LO (pulled to regs), pass1 = HI (stays in LDS) ----
  short8 wlo[NTT];
  for (int pass = 0; pass < 2; ++pass) {
    for (int idx = tid; idx < NT * 512; idx += NTHR_) {
      int tile = idx >> 9, r = idx & 511, ln = r >> 3, j = r & 7;
      int k = tile * 32 + 4 * (ln >> 4) + (j & 3) + 16 * (j >> 2);
      int n = 4 * a + (ln & 3);
      int g = (ln & 15) >> 2;
      float wvv = (k < K1) ? Wxp[((size_t)g * K1 + k) * H_ + n]
                           : Whp[((size_t)g * H_ + (k - K1)) * H_ + n];
      unsigned short hi, lo; splitHL(wvv, hi, lo);
      Wsh[idx] = pass ? hi : lo;
    }
    __syncthreads();
    if (pass == 0) {
      #pragma unroll
      for (int tt = 0; tt < NTT; ++tt) {
        int tile = 2 * tt + kh;
        wlo[tt] = *(const short8*)(Wsh + tile * 512 + lane * 8);
      }
      __syncthreads();   // all pulled before HI overwrites
    }
  }

  const float biasv = bxp[(size_t)(cc >> 2) * H_ + 4 * a + (cc & 3)];
  float cst[4] = {0.f, 0.f, 0.f, 0.f};

  for (int t = 0; t < T_; ++t) {
    const int sp = (t - 1) & (D_ - 1);
    const int sc = t & (D_ - 1);
    float bv = (kh == 0) ? biasv : 0.f;
    float4v acc0 = {bv, bv, bv, bv};
    float4v acc1 = {0.f, 0.f, 0.f, 0.f};

    uint4v w0[8], w1[8];

    auto issue_x = [&](int tt) {   // L0 tiles 0..3 (plain cached: x is read-only)
      const int tile = 2 * tt + kh;
      const float* xp = x + ((size_t)brow * T_ + t) * I_ + tile * 32 + 4 * qq;
      asm volatile("global_load_dwordx4 %0, %2, off\n\t"
                   "global_load_dwordx4 %1, %2, off offset:64"
                   : "=&v"(w0[tt & 7]), "=&v"(w1[tt & 7]) : "v"(xp) : "memory");
    };
    auto issue_ring = [&](int tt) {  // sc0: L1-bypass, L2-CACHED (XCD sharing)
      const uint32_t* p;
      const int tile = 2 * tt + kh;
      if (!LAYER)      p = ring0 + roff(sp, bg, tile - 8, lane);
      else if (tt < 8) p = ring0 + roff(sc, bg, tile, lane);
      else             p = ring1 + roff(sp, bg, tile - 16, lane);
      asm volatile("global_load_dwordx4 %0, %2, off sc0\n\t"
                   "global_load_dwordx4 %1, %2, off offset:16 sc0"
                   : "=&v"(w0[tt & 7]), "=&v"(w1[tt & 7]) : "v"(p) : "memory");
    };
    auto proc_x = [&](int tt) {
      const int tile = 2 * tt + kh;
      short8 ahi, alo;
      #pragma unroll
      for (int j = 0; j < 4; ++j) {
        unsigned short hh, ll;
        splitHL(__uint_as_float(w0[tt & 7][j]), hh, ll); ahi[j] = (short)hh; alo[j] = (short)ll;
        splitHL(__uint_as_float(w1[tt & 7][j]), hh, ll); ahi[j + 4] = (short)hh; alo[j + 4] = (short)ll;
      }
      short8 bhi = *(const short8*)(Wsh + tile * 512 + lane * 8);
      float4v& A = (tt & 1) ? acc1 : acc0;
      A = MFMA16(ahi, bhi, A);
      A = MFMA16(alo, bhi, A);
      A = MFMA16(ahi, wlo[tt], A);
    };
    auto proc_ring = [&](int tt) {
      const int tile = 2 * tt + kh;
      short8 ahi, alo;
      unpack8(w0[tt & 7], w1[tt & 7], ahi, alo);
      short8 bhi = *(const short8*)(Wsh + tile * 512 + lane * 8);
      float4v& A = (tt & 1) ? acc1 : acc0;
      A = MFMA16(ahi, bhi, A);
      A = MFMA16(alo, bhi, A);
      A = MFMA16(ahi, wlo[tt], A);
    };

    // ---- per-XCD epoch inv (wave1 lane0): dedup'd, off critical path ----
    auto epoch_inv = [&]() {
      if (tid == 64) {
        uint32_t old = __hip_atomic_fetch_max(&xcd_ep[xcd * 16], (uint32_t)(t + 1),
                                              __ATOMIC_RELAXED, __HIP_MEMORY_SCOPE_AGENT);
        if (old < (uint32_t)(t + 1))
          asm volatile("buffer_inv sc1" ::: "memory");
      }
    };

    if constexpr (!LAYER) {
      // x partial BEFORE the wait (hidden under poll)
      #pragma unroll
      for (int tt = 0; tt < 4; ++tt) issue_x(tt);
      WAITV(4);
      proc_x(0); proc_x(1);
      WAITV(0);
      proc_x(2); proc_x(3);
      epoch_inv();
      // L0@t: all L0 done t-1; L1 done t-8 (slot t&7 free)
      if (tid == 0) poll2(done + 0, 512 * t, done + 16, 512 * (t - (D_ - 1)));
      __syncthreads();
      #pragma unroll
      for (int tt = 4; tt < 12; ++tt) issue_ring(tt);
      WAITV(8);
      proc_ring(4); proc_ring(5); proc_ring(6); proc_ring(7);
      WAITV(0);
      proc_ring(8); proc_ring(9); proc_ring(10); proc_ring(11);
    } else {
      epoch_inv();
      // h0[t] ready (stale-satisfied when L0 runs ahead)
      if (tid == 0) poll1(done + 0, 512 * (t + 1));
      __syncthreads();
      #pragma unroll
      for (int tt = 0; tt < 8; ++tt) issue_ring(tt);
      WAITV(8);
      proc_ring(0); proc_ring(1); proc_ring(2); proc_ring(3);
      WAITV(0);
      proc_ring(4); proc_ring(5); proc_ring(6); proc_ring(7);
      // own-layer barrier: h1[t-1] ready (overlapped with ring0 compute above)
      if (tid == 0) poll1(done + 16, 512 * t);
      __syncthreads();
      #pragma unroll
      for (int tt = 8; tt < 16; ++tt) issue_ring(tt);
      WAITV(8);
      proc_ring(8); proc_ring(9); proc_ring(10); proc_ring(11);
      WAITV(0);
      proc_ring(12); proc_ring(13); proc_ring(14); proc_ring(15);
    }

    float4v acc = acc0 + acc1;

    // ---- split-K reduction through LDS ----
    if (kh == 1) *(float4v*)(red + ((bg << 6) + lane) * 4) = acc;
    __syncthreads();
    if (kh == 0) {
      acc += *(const float4v*)(red + ((bg << 6) + lane) * 4);

      // activations: cols 0-11 sigmoid (i,f,o), 12-15 tanh (g)
      const bool isg = cc >= 12;
      float av[4];
      #pragma unroll
      for (int i = 0; i < 4; ++i) {
        float xg = acc[i];
        float arg = isg ? xg + xg : xg;
        float e = __expf(-fabsf(arg));
        float s = (arg >= 0.f) ? 1.f / (1.f + e) : e / (1.f + e);
        av[i] = isg ? (s + s - 1.f) : s;   // tanh(x) = 2*sigmoid(2x)-1
      }
      float hn[4];
      #pragma unroll
      for (int i = 0; i < 4; ++i) {
        float fv = __shfl_xor(av[i], 4);
        float ov = __shfl_xor(av[i], 8);
        float gv = __shfl_xor(av[i], 12);
        float cn = fv * cst[i] + av[i] * gv;
        cst[i] = cn;
        float e2 = __expf(-2.f * fabsf(cn));
        float th = (1.f - e2) / (1.f + e2);
        hn[i] = ov * ((cn >= 0.f) ? th : -th);
      }
      // in-wave transpose: lane (qq, cc) gathers row 4qq+cc, cols 4a+0..3
      float v0[4], v1[4], v2[4], v3[4];
      #pragma unroll
      for (int d = 0; d < 4; ++d) {
        int src = (lane & 0x30) | d;
        v0[d] = __shfl(hn[0], src);
        v1[d] = __shfl(hn[1], src);
        v2[d] = __shfl(hn[2], src);
        v3[d] = __shfl(hn[3], src);
      }
      if (cc < 4) {
        uint4v pk; float4v hf;
        #pragma unroll
        for (int d = 0; d < 4; ++d) {
          float hv = (cc == 0) ? v0[d] : (cc == 1) ? v1[d] : (cc == 2) ? v2[d] : v3[d];
          hf[d] = hv;
          unsigned short hh, ll; splitHL(hv, hh, ll);
          pk[d] = ((uint32_t)hh << 16) | (uint32_t)ll;
        }
        // fragment-layout store: lane' = 16*(a&3) + (4qq+cc), words 4*((a>>2)&1)+d
        uint32_t* dst = (LAYER ? ring1 : ring0)
                      + roff(sc, bg, a >> 3, 16 * (a & 3) + 4 * qq + cc)
                      + 4 * ((a >> 2) & 1);
        asm volatile("global_store_dwordx4 %0, %1, off sc0 sc1"
                     :: "v"(dst), "v"(pk) : "memory");
        if (LAYER && t == T_ - 1) {
          float4v* hp = (float4v*)(h1f + (size_t)(bg * 16 + 4 * qq + cc) * H_ + 4 * a);
          asm volatile("global_store_dwordx4 %0, %1, off sc0 sc1"
                       :: "v"(hp), "v"(hf) : "memory");
        }
      }
      // per-wave publish: drain own stores (acked at MALL), then count up.
      if (lane == 0) {
        asm volatile("s_waitcnt vmcnt(0)" ::: "memory");
        __hip_atomic_fetch_add(&done[LAYER * 16 + bg], 1u,
                               __ATOMIC_RELAXED, __HIP_MEMORY_SCOPE_AGENT);
      }
    }
    // NO end-of-step barrier: next step's post-poll __syncthreads orders the
    // red-buffer reuse (kh1 writes at t+1 happen only after all waves pass it).
  }
}

__global__ __launch_bounds__(NTHR_, 2) void lstm_persist(
    const float* __restrict__ x,
    const float* __restrict__ Wx0, const float* __restrict__ bx0, const float* __restrict__ Wh0,
    const float* __restrict__ Wx1, const float* __restrict__ bx1, const float* __restrict__ Wh1,
    uint32_t* done, uint32_t* xcd_ep,
    uint32_t* ring0, uint32_t* ring1,
    float* h1f)
{
  __shared__ unsigned short Wsh[16384];  // 32 KB: W-hi frags
  __shared__ float red[1024];            // 4 KB: split-K reduction
  if (blockIdx.x < G0_)
    run_layer<0>(blockIdx.x, x, Wx0, bx0, Wh0, done, xcd_ep, ring0, ring1, h1f, Wsh, red);
  else
    run_layer<1>(blockIdx.x - G0_, x, Wx1, bx1, Wh1, done, xcd_ep, ring0, ring1, h1f, Wsh, red);
}

__global__ void fc_out(const float* __restrict__ h1f, const float* __restrict__ Wfc,
                       const float* __restrict__ bfc, float* __restrict__ out)
{
  int tid = threadIdx.x;     // 512 threads: 64 batches x 8 partials
  int b = tid >> 3, p = tid & 7;
  const float* hp = h1f + (size_t)b * H_ + p * 64;
  const float* wp = Wfc + p * 64;
  float4v hv[16];
  #pragma unroll
  for (int q = 0; q < 16; ++q)
    asm volatile("global_load_dwordx4 %0, %1, off sc0 sc1"
                 : "=&v"(hv[q]) : "v"(hp + 4 * q) : "memory");
  asm volatile("s_waitcnt vmcnt(0)" ::: "memory");
  float s = 0.f;
  #pragma unroll
  for (int q = 0; q < 16; ++q) {
    float4v wv = *(const float4v*)(wp + 4 * q);
    s += hv[q][0] * wv[0] + hv[q][1] * wv[1] + hv[q][2] * wv[2] + hv[q][3] * wv[3];
  }
  s += __shfl_xor(s, 1);
  s += __shfl_xor(s, 2);
  s += __shfl_xor(s, 4);
  if (p == 0) out[b] = s + bfc[0];
}

extern "C" void kernel_launch(void* const* d_in, const int* in_sizes, int n_in,
                              void* d_out, int out_size, void* d_ws, size_t ws_size,
                              hipStream_t stream)
{
  const float* x   = (const float*)d_in[0];
  const float* Wx0 = (const float*)d_in[1];
  const float* bx0 = (const float*)d_in[2];
  const float* Wh0 = (const float*)d_in[3];
  const float* Wx1 = (const float*)d_in[4];
  const float* bx1 = (const float*)d_in[5];
  const float* Wh1 = (const float*)d_in[6];
  const float* Wfc = (const float*)d_in[7];
  const float* bfc = (const float*)d_in[8];

  uint8_t* ws = (uint8_t*)d_ws;
  uint32_t* done   = (uint32_t*)ws;                    // u32[32]: [0..3] L0, [16..19] L1
  uint32_t* xcd_ep = (uint32_t*)(ws + 512);            // u32[8*16], one line per XCD
  const size_t RINGB = (size_t)D_ * 4 * 16 * 512 * 4;  // 1 MB per ring (u32 frag layout)
  uint32_t* ring0 = (uint32_t*)(ws + 4096);
  uint32_t* ring1 = (uint32_t*)(ws + 4096 + RINGB);
  float* h1f = (float*)(ws + 4096 + 2 * RINGB);        // 128 KB, fully rewritten each call

  // counters + epochs + rings must be zero every call (slot D-1 is the t=-1 state)
  (void)hipMemsetAsync(ws, 0, 4096 + 2 * RINGB, stream);

  hipLaunchKernelGGL(lstm_persist, dim3(G0_ + G1_), dim3(NTHR_), 0, stream,
                     x, Wx0, bx0, Wh0, Wx1, bx1, Wh1,
                     done, xcd_ep, ring0, ring1, h1f);
  hipLaunchKernelGGL(fc_out, dim3(1), dim3(512), 0, stream,
                     h1f, Wfc, bfc, (float*)d_out);
}

// Round 7
// 3826.781 us; speedup vs baseline: 1.9261x; 1.9261x over previous
//
#include <hip/hip_runtime.h>
#include <stdint.h>

#define B_ 64
#define T_ 512
#define I_ 256
#define H_ 512
#define G0_ 128
#define G1_ 128
#define NTHR_ 512
#define D_ 8   // ring depth in CYC fallback mode (power of 2)

typedef __attribute__((ext_vector_type(8))) short short8;
typedef __attribute__((ext_vector_type(4))) float float4v;
typedef __attribute__((ext_vector_type(4))) unsigned int uint4v;

static_assert(sizeof(short8) == 16, "");
static_assert(sizeof(uint4v) == 16, "");

#define SLOTU32 (4 * 16 * 64 * 8)   // u32 per ring slot (bg,ktile,lane,j)

// ---- bf16 helpers (round-to-nearest-even) ----
__device__ __forceinline__ unsigned short f2bf(float x) {
  union { float f; uint32_t u; } v; v.f = x;
  uint32_t r = v.u + 0x7FFFu + ((v.u >> 16) & 1u);
  return (unsigned short)(r >> 16);
}
__device__ __forceinline__ float bf2f(unsigned short h) {
  union { uint32_t u; float f; } v; v.u = ((uint32_t)h) << 16; return v.f;
}
__device__ __forceinline__ void splitHL(float x, unsigned short& hi, unsigned short& lo) {
  hi = f2bf(x);
  lo = f2bf(x - bf2f(hi));   // x - hi is exact in fp32
}

// ring element offset (u32 units). fragment layout: [slot][bg][ktile][lane][j]
// each lane's 8 u32 words are CONTIGUOUS (lane*8).
__device__ __forceinline__ size_t roff(int slot, int bg, int ht, int lane) {
  return ((size_t)((slot * 4 + bg) * 16 + ht)) * 512 + (size_t)lane * 8;
}

// per-thread spin on a single progress word (bypass load, no fences)
__device__ __forceinline__ void wait_ge(const uint32_t* p, int tgt) {
  if (tgt <= 0) return;
  int it = 0;
  while ((int)__hip_atomic_load(p, __ATOMIC_RELAXED, __HIP_MEMORY_SCOPE_AGENT) < tgt) {
    __builtin_amdgcn_s_sleep(1);
    if (++it > 2000000) break;   // safety: degrade to wrong answer, never hang
  }
}

__device__ __forceinline__ void unpack8(uint4v w0, uint4v w1, short8& hi, short8& lo) {
  #pragma unroll
  for (int j = 0; j < 4; ++j) {
    hi[j]     = (short)(w0[j] >> 16); lo[j]     = (short)(w0[j] & 0xffffu);
    hi[j + 4] = (short)(w1[j] >> 16); lo[j + 4] = (short)(w1[j] & 0xffffu);
  }
}

#define MFMA16(A, Bv, C) __builtin_amdgcn_mfma_f32_16x16x32_bf16(A, Bv, C, 0, 0, 0)

// counted wait on our asm-issued vmem + scheduling fence (rule #18)
#define WAITV(n) do { \
    asm volatile("s_waitcnt vmcnt(" #n ")" ::: "memory"); \
    __builtin_amdgcn_sched_barrier(0); \
  } while (0)

// One LSTM layer, persistent across all T steps.
// Block 'a' owns h-columns [4a, 4a+4) -> 16 gate columns (4 gates x 4 cols).
// MFMA frag conventions: k(q,j) = 4q + (j&3) + 16*(j>>2), q = lane>>4
//   A: row m = lane&15, B: col = lane&15
//   C/D: col = lane&15, row = 4*(lane>>4) + i   (m89-verified)
//
// FULL mode (write-once rings, T+1 slots, slot s holds h[s-1], slot0 = zeros):
//   ring reads are PLAIN CACHED loads. Safe because every ring address is
//   written exactly once per launch (write-through sc0 sc1 + drain before
//   flag), and readers touch a line only after its flag -> first L2 fill is
//   always fresh; no invalidation needed anywhere. Flags: per-WAVE words
//   prog[bg*128+a] (stores, never RMW); all 512 threads poll one word each.
// CYC mode (fallback, ws too small): exact round-5 protocol — D=8 ring,
//   sc0 sc1 bypass reads, 128 per-block flags, end-of-step barrier.
template <int LAYER, bool FULL>
__device__ void run_layer(
    int a,
    const float* __restrict__ x,
    const float* __restrict__ Wxp, const float* __restrict__ bxp,
    const float* __restrict__ Whp,
    uint32_t* prog0, uint32_t* prog1,
    uint32_t* ring0, uint32_t* ring1,
    float* h1f,
    unsigned short* Wsh, float* red)
{
  constexpr int K1 = LAYER ? H_ : I_;
  constexpr int NT = (K1 + H_) / 32;   // 24 (L0) or 32 (L1) K-tiles
  constexpr int NTT = NT / 2;          // 12 or 16 tiles per k-half wavegroup
  const int tid = threadIdx.x;
  const int lane = tid & 63;
  const int wid = tid >> 6;     // 0..7
  const int bg = wid & 3;       // batch group (16 batches)
  const int kh = wid >> 2;      // K-half (parity of tile)
  const int qq = lane >> 4;
  const int cc = lane & 15;     // A-row / gate column within block
  const int brow = bg * 16 + cc;

  // ---- stage weight slice: pass0 = LO (pulled to regs), pass1 = HI (stays in LDS) ----
  short8 wlo[NTT];
  for (int pass = 0; pass < 2; ++pass) {
    for (int idx = tid; idx < NT * 512; idx += NTHR_) {
      int tile = idx >> 9, r = idx & 511, ln = r >> 3, j = r & 7;
      int k = tile * 32 + 4 * (ln >> 4) + (j & 3) + 16 * (j >> 2);
      int n = 4 * a + (ln & 3);
      int g = (ln & 15) >> 2;
      float wvv = (k < K1) ? Wxp[((size_t)g * K1 + k) * H_ + n]
                           : Whp[((size_t)g * H_ + (k - K1)) * H_ + n];
      unsigned short hi, lo; splitHL(wvv, hi, lo);
      Wsh[idx] = pass ? hi : lo;
    }
    __syncthreads();
    if (pass == 0) {
      #pragma unroll
      for (int tt = 0; tt < NTT; ++tt) {
        int tile = 2 * tt + kh;
        wlo[tt] = *(const short8*)(Wsh + tile * 512 + lane * 8);
      }
      __syncthreads();   // all pulled before HI overwrites
    }
  }

  const float biasv = bxp[(size_t)(cc >> 2) * H_ + 4 * a + (cc & 3)];
  float cst[4] = {0.f, 0.f, 0.f, 0.f};

  uint32_t* myprog = LAYER ? prog1 : prog0;

  for (int t = 0; t < T_; ++t) {
    const int slot_prev = FULL ? t       : ((t - 1) & (D_ - 1));  // h[t-1]
    const int slot_cur  = FULL ? (t + 1) : (t & (D_ - 1));        // h[t] (write; L1 reads h0[t])
    float bv = (kh == 0) ? biasv : 0.f;
    float4v acc0 = {bv, bv, bv, bv};
    float4v acc1 = {0.f, 0.f, 0.f, 0.f};

    uint4v w0[8], w1[8];

    auto issue_x = [&](int tt) {   // L0 tiles 0..3 (x is read-only: cached)
      const int tile = 2 * tt + kh;
      const float* xp = x + ((size_t)brow * T_ + t) * I_ + tile * 32 + 4 * qq;
      asm volatile("global_load_dwordx4 %0, %2, off\n\t"
                   "global_load_dwordx4 %1, %2, off offset:64"
                   : "=&v"(w0[tt & 7]), "=&v"(w1[tt & 7]) : "v"(xp) : "memory");
    };
    auto issue_ring = [&](int tt) {
      const int tile = 2 * tt + kh;
      const uint32_t* p;
      if (!LAYER)      p = ring0 + roff(slot_prev, bg, tile - 8, lane);
      else if (tt < 8) p = ring0 + roff(slot_cur,  bg, tile,      lane);
      else             p = ring1 + roff(slot_prev, bg, tile - 16, lane);
      if constexpr (FULL) {   // write-once slots: plain cached (L2-shared per XCD)
        asm volatile("global_load_dwordx4 %0, %2, off\n\t"
                     "global_load_dwordx4 %1, %2, off offset:16"
                     : "=&v"(w0[tt & 7]), "=&v"(w1[tt & 7]) : "v"(p) : "memory");
      } else {                // circular slots: must bypass (stale L2 possible)
        asm volatile("global_load_dwordx4 %0, %2, off sc0 sc1\n\t"
                     "global_load_dwordx4 %1, %2, off offset:16 sc0 sc1"
                     : "=&v"(w0[tt & 7]), "=&v"(w1[tt & 7]) : "v"(p) : "memory");
      }
    };
    auto proc_x = [&](int tt) {
      const int tile = 2 * tt + kh;
      short8 ahi, alo;
      #pragma unroll
      for (int j = 0; j < 4; ++j) {
        unsigned short hh, ll;
        splitHL(__uint_as_float(w0[tt & 7][j]), hh, ll); ahi[j] = (short)hh; alo[j] = (short)ll;
        splitHL(__uint_as_float(w1[tt & 7][j]), hh, ll); ahi[j + 4] = (short)hh; alo[j + 4] = (short)ll;
      }
      short8 bhi = *(const short8*)(Wsh + tile * 512 + lane * 8);
      float4v& A = (tt & 1) ? acc1 : acc0;
      A = MFMA16(ahi, bhi, A);
      A = MFMA16(alo, bhi, A);
      A = MFMA16(ahi, wlo[tt], A);
    };
    auto proc_ring = [&](int tt) {
      const int tile = 2 * tt + kh;
      short8 ahi, alo;
      unpack8(w0[tt & 7], w1[tt & 7], ahi, alo);
      short8 bhi = *(const short8*)(Wsh + tile * 512 + lane * 8);
      float4v& A = (tt & 1) ? acc1 : acc0;
      A = MFMA16(ahi, bhi, A);
      A = MFMA16(alo, bhi, A);
      A = MFMA16(ahi, wlo[tt], A);
    };

    if constexpr (!LAYER) {
      // x prefetch issued BEFORE the wait (latency hidden under poll)
      #pragma unroll
      for (int tt = 0; tt < 4; ++tt) issue_x(tt);
      if constexpr (FULL) {
        wait_ge(&prog0[tid], t);      // own-layer recurrence; no backpressure
      } else {
        if (tid < 128)      wait_ge(&prog0[tid], t);
        else if (tid < 256) wait_ge(&prog1[tid - 128], t - (D_ - 1));
      }
      __syncthreads();
      #pragma unroll
      for (int tt = 4; tt < 8; ++tt) issue_ring(tt);
      WAITV(8);                        // x loads landed
      proc_x(0); proc_x(1); proc_x(2); proc_x(3);
      #pragma unroll
      for (int tt = 8; tt < 12; ++tt) issue_ring(tt);
      WAITV(8);                        // ring tiles 4..7 landed
      proc_ring(4); proc_ring(5); proc_ring(6); proc_ring(7);
      WAITV(0);
      proc_ring(8); proc_ring(9); proc_ring(10); proc_ring(11);
    } else {
      if constexpr (FULL) {
        wait_ge(&prog0[tid], t + 1);  // h0[t] ready
      } else {
        if (tid < 128)      wait_ge(&prog0[tid], t + 1);
        else if (tid < 256) wait_ge(&prog1[tid - 128], t);
      }
      __syncthreads();
      #pragma unroll
      for (int tt = 0; tt < 8; ++tt) issue_ring(tt);
      WAITV(8);
      proc_ring(0); proc_ring(1); proc_ring(2); proc_ring(3);
      WAITV(0);
      proc_ring(4); proc_ring(5); proc_ring(6); proc_ring(7);
      if constexpr (FULL) {            // own-layer wait, overlapped with h0 half
        wait_ge(&prog1[tid], t);
        __syncthreads();
      }
      #pragma unroll
      for (int tt = 8; tt < 16; ++tt) issue_ring(tt);
      WAITV(8);
      proc_ring(8); proc_ring(9); proc_ring(10); proc_ring(11);
      WAITV(0);
      proc_ring(12); proc_ring(13); proc_ring(14); proc_ring(15);
    }

    float4v acc = acc0 + acc1;

    // ---- split-K reduction through LDS ----
    if (kh == 1) *(float4v*)(red + ((bg << 6) + lane) * 4) = acc;
    __syncthreads();
    if (kh == 0) {
      acc += *(const float4v*)(red + ((bg << 6) + lane) * 4);

      // activations: cols 0-11 sigmoid (i,f,o), 12-15 tanh (g)
      const bool isg = cc >= 12;
      float av[4];
      #pragma unroll
      for (int i = 0; i < 4; ++i) {
        float xg = acc[i];
        float arg = isg ? xg + xg : xg;
        float e = __expf(-fabsf(arg));
        float s = (arg >= 0.f) ? 1.f / (1.f + e) : e / (1.f + e);
        av[i] = isg ? (s + s - 1.f) : s;   // tanh(x) = 2*sigmoid(2x)-1
      }
      float hn[4];
      #pragma unroll
      for (int i = 0; i < 4; ++i) {
        float fv = __shfl_xor(av[i], 4);
        float ov = __shfl_xor(av[i], 8);
        float gv = __shfl_xor(av[i], 12);
        float cn = fv * cst[i] + av[i] * gv;
        cst[i] = cn;
        float e2 = __expf(-2.f * fabsf(cn));
        float th = (1.f - e2) / (1.f + e2);
        hn[i] = ov * ((cn >= 0.f) ? th : -th);
      }
      // in-wave transpose: lane (qq, cc) gathers row 4qq+cc, cols 4a+0..3
      float v0[4], v1[4], v2[4], v3[4];
      #pragma unroll
      for (int d = 0; d < 4; ++d) {
        int src = (lane & 0x30) | d;
        v0[d] = __shfl(hn[0], src);
        v1[d] = __shfl(hn[1], src);
        v2[d] = __shfl(hn[2], src);
        v3[d] = __shfl(hn[3], src);
      }
      if (cc < 4) {
        uint4v pk; float4v hf;
        #pragma unroll
        for (int d = 0; d < 4; ++d) {
          float hv = (cc == 0) ? v0[d] : (cc == 1) ? v1[d] : (cc == 2) ? v2[d] : v3[d];
          hf[d] = hv;
          unsigned short hh, ll; splitHL(hv, hh, ll);
          pk[d] = ((uint32_t)hh << 16) | (uint32_t)ll;
        }
        // fragment-layout store: lane' = 16*(a&3) + (4qq+cc), words 4*((a>>2)&1)+d
        uint32_t* dst = (LAYER ? ring1 : ring0)
                      + roff(slot_cur, bg, a >> 3, 16 * (a & 3) + 4 * qq + cc)
                      + 4 * ((a >> 2) & 1);
        asm volatile("global_store_dwordx4 %0, %1, off sc0 sc1"
                     :: "v"(dst), "v"(pk) : "memory");
        if (LAYER && t == T_ - 1) {
          float4v* hp = (float4v*)(h1f + (size_t)(bg * 16 + 4 * qq + cc) * H_ + 4 * a);
          asm volatile("global_store_dwordx4 %0, %1, off sc0 sc1"
                       :: "v"(hp), "v"(hf) : "memory");
        }
      }
      if constexpr (FULL) {
        // per-WAVE publish: drain only this wave's stores, then one flag store.
        // No end-of-step barrier needed: red-buffer reuse at t+1 is ordered by
        // the post-poll __syncthreads (kh1 writes red only after that barrier).
        asm volatile("s_waitcnt vmcnt(0)" ::: "memory");
        if (lane == 0)
          __hip_atomic_store(&myprog[bg * 128 + a], (uint32_t)(t + 1),
                             __ATOMIC_RELAXED, __HIP_MEMORY_SCOPE_AGENT);
      }
    }
    if constexpr (!FULL) {
      // round-5 protocol: collective drain + barrier + per-block flag
      asm volatile("s_waitcnt vmcnt(0)" ::: "memory");
      __syncthreads();
      if (tid == 0)
        __hip_atomic_store(&myprog[a], (uint32_t)(t + 1),
                           __ATOMIC_RELAXED, __HIP_MEMORY_SCOPE_AGENT);
    }
  }
}

template <bool FULL>
__global__ __launch_bounds__(NTHR_, 2) void lstm_persist(
    const float* __restrict__ x,
    const float* __restrict__ Wx0, const float* __restrict__ bx0, const float* __restrict__ Wh0,
    const float* __restrict__ Wx1, const float* __restrict__ bx1, const float* __restrict__ Wh1,
    uint32_t* prog0, uint32_t* prog1,
    uint32_t* ring0, uint32_t* ring1,
    float* h1f)
{
  __shared__ unsigned short Wsh[16384];  // 32 KB: W-hi frags
  __shared__ float red[1024];            // 4 KB: split-K reduction
  if (blockIdx.x < G0_)
    run_layer<0, FULL>(blockIdx.x, x, Wx0, bx0, Wh0, prog0, prog1, ring0, ring1, h1f, Wsh, red);
  else
    run_layer<1, FULL>(blockIdx.x - G0_, x, Wx1, bx1, Wh1, prog0, prog1, ring0, ring1, h1f, Wsh, red);
}

__global__ void fc_out(const float* __restrict__ h1f, const float* __restrict__ Wfc,
                       const float* __restrict__ bfc, float* __restrict__ out)
{
  int tid = threadIdx.x;     // 512 threads: 64 batches x 8 partials
  int b = tid >> 3, p = tid & 7;
  const float* hp = h1f + (size_t)b * H_ + p * 64;
  const float* wp = Wfc + p * 64;
  float4v hv[16];
  #pragma unroll
  for (int q = 0; q < 16; ++q)
    asm volatile("global_load_dwordx4 %0, %1, off sc0 sc1"
                 : "=&v"(hv[q]) : "v"(hp + 4 * q) : "memory");
  asm volatile("s_waitcnt vmcnt(0)" ::: "memory");
  float s = 0.f;
  #pragma unroll
  for (int q = 0; q < 16; ++q) {
    float4v wv = *(const float4v*)(wp + 4 * q);
    s += hv[q][0] * wv[0] + hv[q][1] * wv[1] + hv[q][2] * wv[2] + hv[q][3] * wv[3];
  }
  s += __shfl_xor(s, 1);
  s += __shfl_xor(s, 2);
  s += __shfl_xor(s, 4);
  if (p == 0) out[b] = s + bfc[0];
}

extern "C" void kernel_launch(void* const* d_in, const int* in_sizes, int n_in,
                              void* d_out, int out_size, void* d_ws, size_t ws_size,
                              hipStream_t stream)
{
  const float* x   = (const float*)d_in[0];
  const float* Wx0 = (const float*)d_in[1];
  const float* bx0 = (const float*)d_in[2];
  const float* Wh0 = (const float*)d_in[3];
  const float* Wx1 = (const float*)d_in[4];
  const float* bx1 = (const float*)d_in[5];
  const float* Wh1 = (const float*)d_in[6];
  const float* Wfc = (const float*)d_in[7];
  const float* bfc = (const float*)d_in[8];

  uint8_t* ws = (uint8_t*)d_ws;
  const size_t SLOTB      = (size_t)SLOTU32 * 4;          // 128 KB per slot
  const size_t RINGB_FULL = (size_t)(T_ + 1) * SLOTB;     // 67.2 MB per ring
  const size_t RINGB_CYC  = (size_t)D_ * SLOTB;           // 1 MB per ring
  const size_t NEED_FULL  = 4096 + 2 * RINGB_FULL + (size_t)B_ * H_ * 4;

  uint32_t* prog0 = (uint32_t*)ws;              // FULL: 512 words; CYC: 128
  uint32_t* prog1 = (uint32_t*)(ws + 2048);

  if (ws_size >= NEED_FULL) {
    uint32_t* ring0 = (uint32_t*)(ws + 4096);
    uint32_t* ring1 = (uint32_t*)(ws + 4096 + RINGB_FULL);
    float* h1f = (float*)(ws + 4096 + 2 * RINGB_FULL);
    // zero: flags + ring0 slot0 (contiguous), then ring1 slot0 (h[-1] = 0)
    (void)hipMemsetAsync(ws, 0, 4096 + SLOTB, stream);
    (void)hipMemsetAsync(ring1, 0, SLOTB, stream);
    hipLaunchKernelGGL(lstm_persist<true>, dim3(G0_ + G1_), dim3(NTHR_), 0, stream,
                       x, Wx0, bx0, Wh0, Wx1, bx1, Wh1,
                       prog0, prog1, ring0, ring1, h1f);
    hipLaunchKernelGGL(fc_out, dim3(1), dim3(512), 0, stream,
                       h1f, Wfc, bfc, (float*)d_out);
  } else {
    uint32_t* ring0 = (uint32_t*)(ws + 4096);
    uint32_t* ring1 = (uint32_t*)(ws + 4096 + RINGB_CYC);
    float* h1f = (float*)(ws + 4096 + 2 * RINGB_CYC);
    (void)hipMemsetAsync(ws, 0, 4096 + 2 * RINGB_CYC, stream);
    hipLaunchKernelGGL(lstm_persist<false>, dim3(G0_ + G1_), dim3(NTHR_), 0, stream,
                       x, Wx0, bx0, Wh0, Wx1, bx1, Wh1,
                       prog0, prog1, ring0, ring1, h1f);
    hipLaunchKernelGGL(fc_out, dim3(1), dim3(512), 0, stream,
                       h1f, Wfc, bfc, (float*)d_out);
  }
}

// Round 8
// 3004.938 us; speedup vs baseline: 2.4529x; 1.2735x over previous
//
#include <hip/hip_runtime.h>
#include <stdint.h>

#define B_ 64
#define T_ 512
#define I_ 256
#define H_ 512
#define G0_ 128
#define G1_ 128
#define NTHR_ 512
#define D_ 8   // ring depth in CYC fallback mode

typedef __attribute__((ext_vector_type(8))) short short8;
typedef __attribute__((ext_vector_type(4))) float float4v;
typedef __attribute__((ext_vector_type(4))) unsigned int uint4v;
typedef __attribute__((ext_vector_type(2))) unsigned int uint2v;

static_assert(sizeof(short8) == 16, "");

#define TILE_B 2048                    // per (bg,ktile): 1KB hi frags + 1KB lo frags
#define SLOT_B ((size_t)4 * 16 * TILE_B)  // 128 KB per slot

// ---- bf16 helpers (round-to-nearest-even) ----
__device__ __forceinline__ unsigned short f2bf(float x) {
  union { float f; uint32_t u; } v; v.f = x;
  uint32_t r = v.u + 0x7FFFu + ((v.u >> 16) & 1u);
  return (unsigned short)(r >> 16);
}
__device__ __forceinline__ float bf2f(unsigned short h) {
  union { uint32_t u; float f; } v; v.u = ((uint32_t)h) << 16; return v.f;
}
__device__ __forceinline__ void splitHL(float x, unsigned short& hi, unsigned short& lo) {
  hi = f2bf(x);
  lo = f2bf(x - bf2f(hi));   // x - hi is exact in fp32
}

// byte offset of a lane's hi-frag; lo-frag is at +1024 (same tile)
__device__ __forceinline__ size_t rbyte(int slot, int bg, int ht, int lane) {
  return ((size_t)slot * 64 + bg * 16 + ht) * TILE_B + (size_t)lane * 16;
}

// per-thread spin on one progress word (bypass load)
__device__ __forceinline__ void wait_ge(const uint32_t* p, int tgt) {
  if (tgt <= 0) return;
  int it = 0;
  while ((int)__hip_atomic_load(p, __ATOMIC_RELAXED, __HIP_MEMORY_SCOPE_AGENT) < tgt) {
    __builtin_amdgcn_s_sleep(1);
    if (++it > 2000000) break;   // safety: degrade to wrong answer, never hang
  }
}

#define MFMA16(A, Bv, C) __builtin_amdgcn_mfma_f32_16x16x32_bf16(A, Bv, C, 0, 0, 0)

// counted wait on our asm-issued vmem + scheduling fence (rule #18)
#define WAITV(n) do { \
    asm volatile("s_waitcnt vmcnt(" #n ")" ::: "memory"); \
    __builtin_amdgcn_sched_barrier(0); \
  } while (0)

// One LSTM layer, persistent across all T steps.
// Block 'a' owns h-columns [4a,4a+4) -> 16 gate cols. K: [0,K1)=inp, [K1,K1+512)=h.
// MFMA frags: k(q,j)=4q+(j&3)+16*(j>>2), A-row=lane&15, B-col=lane&15,
// C/D col=lane&15 row=4*(lane>>4)+i (m89-verified).
//
// FULL: write-once rings (T+1 slots, slot s = h[s-1], slot0 zeroed). Reads are
// plain cached (L2-shared per XCD) — safe: every address written once per
// launch, all reads flag-gated, so first L2 fill is always fresh. Split
// hi/lo frags: reader loads short8 directly, zero unpack VALU. Flags: per-wave
// words prog[bg*128+a]; each thread polls ONE word, OWN block's words are
// skipped (intra-block ordering via end-of-step barrier after per-wave drain)
// -> own-flag visibility round trip is off the self-loop.
// CYC (fallback, small ws): D=8 ring, bypass reads, block flags (round-5 proto).
template <int LAYER, bool FULL>
__device__ void run_layer(
    int a,
    const float* __restrict__ x,
    const float* __restrict__ Wxp, const float* __restrict__ bxp,
    const float* __restrict__ Whp,
    uint32_t* prog0, uint32_t* prog1,
    uint8_t* r0, uint8_t* r1,
    float* h1f,
    unsigned short* Wsh, float* red)
{
  constexpr int K1 = LAYER ? H_ : I_;
  constexpr int NT = (K1 + H_) / 32;   // 24 (L0) or 32 (L1) K-tiles
  constexpr int NTT = NT / 2;          // 12 or 16 tiles per k-half wavegroup
  const int tid = threadIdx.x;
  const int lane = tid & 63;
  const int wid = tid >> 6;
  const int bg = wid & 3;       // batch group (16 batches)
  const int kh = wid >> 2;      // K-half (parity of tile)
  const int qq = lane >> 4;
  const int cc = lane & 15;
  const int brow = bg * 16 + cc;

  // ---- stage weight slice: pass0 = LO (to regs), pass1 = HI (stays in LDS) ----
  short8 wlo[NTT];
  for (int pass = 0; pass < 2; ++pass) {
    for (int idx = tid; idx < NT * 512; idx += NTHR_) {
      int tile = idx >> 9, r = idx & 511, ln = r >> 3, j = r & 7;
      int k = tile * 32 + 4 * (ln >> 4) + (j & 3) + 16 * (j >> 2);
      int n = 4 * a + (ln & 3);
      int g = (ln & 15) >> 2;
      float wvv = (k < K1) ? Wxp[((size_t)g * K1 + k) * H_ + n]
                           : Whp[((size_t)g * H_ + (k - K1)) * H_ + n];
      unsigned short hi, lo; splitHL(wvv, hi, lo);
      Wsh[idx] = pass ? hi : lo;
    }
    __syncthreads();
    if (pass == 0) {
      #pragma unroll
      for (int tt = 0; tt < NTT; ++tt) {
        int tile = 2 * tt + kh;
        wlo[tt] = *(const short8*)(Wsh + tile * 512 + lane * 8);
      }
      __syncthreads();
    }
  }

  const float biasv = bxp[(size_t)(cc >> 2) * H_ + 4 * a + (cc & 3)];
  float cst[4] = {0.f, 0.f, 0.f, 0.f};

  uint32_t* myprog = LAYER ? prog1 : prog0;
  const bool ownw = FULL ? ((tid & 127) == a) : false;

  for (int t = 0; t < T_; ++t) {
    const int slotP = FULL ? t       : (t & (D_ - 1));        // h[t-1]
    const int slotC = FULL ? (t + 1) : ((t + 1) & (D_ - 1));  // h[t]
    float bv = (kh == 0) ? biasv : 0.f;
    float4v accA = {bv, bv, bv, bv};   // hi*Whi (+bias)
    float4v accB = {0.f, 0.f, 0.f, 0.f};  // lo*Whi
    float4v accC = {0.f, 0.f, 0.f, 0.f};  // hi*Wlo

    short8 hbuf[8], lbuf[8];
    uint4v xw0[4], xw1[4];

    auto issue_x = [&](int tt) {   // x read-only: cached
      const int tile = 2 * tt + kh;
      const float* xp = x + ((size_t)brow * T_ + t) * I_ + tile * 32 + 4 * qq;
      asm volatile("global_load_dwordx4 %0, %2, off\n\t"
                   "global_load_dwordx4 %1, %2, off offset:64"
                   : "=&v"(xw0[tt]), "=&v"(xw1[tt]) : "v"(xp) : "memory");
    };
    auto proc_x = [&](int tt) {
      const int tile = 2 * tt + kh;
      short8 ahi, alo;
      #pragma unroll
      for (int j = 0; j < 4; ++j) {
        unsigned short hh, ll;
        splitHL(__uint_as_float(xw0[tt][j]), hh, ll); ahi[j] = (short)hh; alo[j] = (short)ll;
        splitHL(__uint_as_float(xw1[tt][j]), hh, ll); ahi[j + 4] = (short)hh; alo[j + 4] = (short)ll;
      }
      short8 bhi = *(const short8*)(Wsh + tile * 512 + lane * 8);
      accA = MFMA16(ahi, bhi, accA);
      accB = MFMA16(alo, bhi, accB);
      accC = MFMA16(ahi, wlo[tt], accC);
    };
    auto issue_ring = [&](int tt) {
      const int tile = 2 * tt + kh;
      const uint8_t* p;
      if (!LAYER)      p = r0 + rbyte(slotP, bg, tile - 8, lane);
      else if (tt < 8) p = r0 + rbyte(slotC, bg, tile, lane);
      else             p = r1 + rbyte(slotP, bg, tile - 16, lane);
      if constexpr (FULL) {
        asm volatile("global_load_dwordx4 %0, %2, off\n\t"
                     "global_load_dwordx4 %1, %2, off offset:1024"
                     : "=&v"(hbuf[tt & 7]), "=&v"(lbuf[tt & 7]) : "v"(p) : "memory");
      } else {
        asm volatile("global_load_dwordx4 %0, %2, off sc0 sc1\n\t"
                     "global_load_dwordx4 %1, %2, off offset:1024 sc0 sc1"
                     : "=&v"(hbuf[tt & 7]), "=&v"(lbuf[tt & 7]) : "v"(p) : "memory");
      }
    };
    auto proc_ring = [&](int tt) {
      const int tile = 2 * tt + kh;
      short8 bhi = *(const short8*)(Wsh + tile * 512 + lane * 8);
      accA = MFMA16(hbuf[tt & 7], bhi, accA);
      accB = MFMA16(lbuf[tt & 7], bhi, accB);
      accC = MFMA16(hbuf[tt & 7], wlo[tt], accC);
    };

    if constexpr (!LAYER) {
      // x partial entirely BEFORE the poll (off the self-loop)
      issue_x(0); issue_x(1); issue_x(2); issue_x(3);
      WAITV(0);
      proc_x(0); proc_x(1); proc_x(2); proc_x(3);
      if constexpr (FULL) {
        if (!ownw) wait_ge(&prog0[tid], t);
      } else {
        if (tid < 128)      wait_ge(&prog0[tid], t);
        else if (tid < 256) wait_ge(&prog1[tid - 128], t - (D_ - 1));
      }
      __syncthreads();
      #pragma unroll
      for (int tt = 4; tt < 12; ++tt) issue_ring(tt);
      WAITV(8);
      proc_ring(4); proc_ring(5); proc_ring(6); proc_ring(7);
      WAITV(0);
      proc_ring(8); proc_ring(9); proc_ring(10); proc_ring(11);
    } else {
      // combined upfront poll: both halves' loads go out in one burst
      if constexpr (FULL) {
        wait_ge(&prog0[tid], t + 1);
        if (!ownw) wait_ge(&prog1[tid], t);
      } else {
        if (tid < 128)      wait_ge(&prog0[tid], t + 1);
        else if (tid < 256) wait_ge(&prog1[tid - 128], t);
      }
      __syncthreads();
      #pragma unroll
      for (int tt = 0; tt < 8; ++tt) issue_ring(tt);
      WAITV(8);
      proc_ring(0); proc_ring(1); proc_ring(2); proc_ring(3);
      issue_ring(8); issue_ring(9); issue_ring(10); issue_ring(11);
      WAITV(8);
      proc_ring(4); proc_ring(5); proc_ring(6); proc_ring(7);
      issue_ring(12); issue_ring(13); issue_ring(14); issue_ring(15);
      WAITV(8);
      proc_ring(8); proc_ring(9); proc_ring(10); proc_ring(11);
      WAITV(0);
      proc_ring(12); proc_ring(13); proc_ring(14); proc_ring(15);
    }

    float4v acc = accA + accB + accC;

    // ---- split-K reduction through LDS ----
    if (kh == 1) *(float4v*)(red + ((bg << 6) + lane) * 4) = acc;
    __syncthreads();
    if (kh == 0) {
      acc += *(const float4v*)(red + ((bg << 6) + lane) * 4);

      // activations: cols 0-11 sigmoid (i,f,o), 12-15 tanh (g)
      const bool isg = cc >= 12;
      float av[4];
      #pragma unroll
      for (int i = 0; i < 4; ++i) {
        float xg = acc[i];
        float arg = isg ? xg + xg : xg;
        float e = __expf(-fabsf(arg));
        float s = (arg >= 0.f) ? 1.f / (1.f + e) : e / (1.f + e);
        av[i] = isg ? (s + s - 1.f) : s;
      }
      float hn[4];
      #pragma unroll
      for (int i = 0; i < 4; ++i) {
        float fv = __shfl_xor(av[i], 4);
        float ov = __shfl_xor(av[i], 8);
        float gv = __shfl_xor(av[i], 12);
        float cn = fv * cst[i] + av[i] * gv;
        cst[i] = cn;
        float e2 = __expf(-2.f * fabsf(cn));
        float th = (1.f - e2) / (1.f + e2);
        hn[i] = ov * ((cn >= 0.f) ? th : -th);
      }
      // in-wave transpose: lane (qq,cc<4) gathers row 4qq+cc, cols 4a+0..3
      float v0[4], v1[4], v2[4], v3[4];
      #pragma unroll
      for (int d = 0; d < 4; ++d) {
        int src = (lane & 0x30) | d;
        v0[d] = __shfl(hn[0], src);
        v1[d] = __shfl(hn[1], src);
        v2[d] = __shfl(hn[2], src);
        v3[d] = __shfl(hn[3], src);
      }
      if (cc < 4) {
        unsigned short hh[4], ll[4]; float4v hf;
        #pragma unroll
        for (int d = 0; d < 4; ++d) {
          float hv = (cc == 0) ? v0[d] : (cc == 1) ? v1[d] : (cc == 2) ? v2[d] : v3[d];
          hf[d] = hv;
          splitHL(hv, hh[d], ll[d]);
        }
        uint2v hi2, lo2;
        hi2[0] = (uint32_t)hh[0] | ((uint32_t)hh[1] << 16);
        hi2[1] = (uint32_t)hh[2] | ((uint32_t)hh[3] << 16);
        lo2[0] = (uint32_t)ll[0] | ((uint32_t)ll[1] << 16);
        lo2[1] = (uint32_t)ll[2] | ((uint32_t)ll[3] << 16);
        // frag store: lane' = 16*(a&3)+(4qq+cc), shorts j0..j0+3, j0=4*((a>>2)&1)
        uint8_t* dst = (LAYER ? r1 : r0)
                     + rbyte(slotC, bg, a >> 3, 16 * (a & 3) + 4 * qq + cc)
                     + 8 * ((a >> 2) & 1);
        asm volatile("global_store_dwordx2 %0, %1, off sc0 sc1\n\t"
                     "global_store_dwordx2 %0, %2, off offset:1024 sc0 sc1"
                     :: "v"(dst), "v"(hi2), "v"(lo2) : "memory");
        if (LAYER && t == T_ - 1) {
          float4v* hp = (float4v*)(h1f + (size_t)(bg * 16 + 4 * qq + cc) * H_ + 4 * a);
          asm volatile("global_store_dwordx4 %0, %1, off sc0 sc1"
                       :: "v"(hp), "v"(hf) : "memory");
        }
      }
    }
    if constexpr (FULL) {
      // per-wave drain + flag (kh0), then end-of-step barrier: own-block
      // consumers are ordered by the barrier, so nobody polls own words.
      if (kh == 0) {
        asm volatile("s_waitcnt vmcnt(0)" ::: "memory");
        if (lane == 0)
          __hip_atomic_store(&myprog[bg * 128 + a], (uint32_t)(t + 1),
                             __ATOMIC_RELAXED, __HIP_MEMORY_SCOPE_AGENT);
      }
      __syncthreads();
    } else {
      asm volatile("s_waitcnt vmcnt(0)" ::: "memory");
      __syncthreads();
      if (tid == 0)
        __hip_atomic_store(&myprog[a], (uint32_t)(t + 1),
                           __ATOMIC_RELAXED, __HIP_MEMORY_SCOPE_AGENT);
    }
  }
}

template <bool FULL>
__global__ __launch_bounds__(NTHR_, 2) void lstm_persist(
    const float* __restrict__ x,
    const float* __restrict__ Wx0, const float* __restrict__ bx0, const float* __restrict__ Wh0,
    const float* __restrict__ Wx1, const float* __restrict__ bx1, const float* __restrict__ Wh1,
    uint32_t* prog0, uint32_t* prog1,
    uint8_t* ring0, uint8_t* ring1,
    float* h1f)
{
  __shared__ unsigned short Wsh[16384];  // 32 KB
  __shared__ float red[1024];            // 4 KB
  if (blockIdx.x < G0_)
    run_layer<0, FULL>(blockIdx.x, x, Wx0, bx0, Wh0, prog0, prog1, ring0, ring1, h1f, Wsh, red);
  else
    run_layer<1, FULL>(blockIdx.x - G0_, x, Wx1, bx1, Wh1, prog0, prog1, ring0, ring1, h1f, Wsh, red);
}

__global__ void fc_out(const float* __restrict__ h1f, const float* __restrict__ Wfc,
                       const float* __restrict__ bfc, float* __restrict__ out)
{
  int tid = threadIdx.x;
  int b = tid >> 3, p = tid & 7;
  const float* hp = h1f + (size_t)b * H_ + p * 64;
  const float* wp = Wfc + p * 64;
  float4v hv[16];
  #pragma unroll
  for (int q = 0; q < 16; ++q)
    asm volatile("global_load_dwordx4 %0, %1, off sc0 sc1"
                 : "=&v"(hv[q]) : "v"(hp + 4 * q) : "memory");
  asm volatile("s_waitcnt vmcnt(0)" ::: "memory");
  float s = 0.f;
  #pragma unroll
  for (int q = 0; q < 16; ++q) {
    float4v wv = *(const float4v*)(wp + 4 * q);
    s += hv[q][0] * wv[0] + hv[q][1] * wv[1] + hv[q][2] * wv[2] + hv[q][3] * wv[3];
  }
  s += __shfl_xor(s, 1);
  s += __shfl_xor(s, 2);
  s += __shfl_xor(s, 4);
  if (p == 0) out[b] = s + bfc[0];
}

extern "C" void kernel_launch(void* const* d_in, const int* in_sizes, int n_in,
                              void* d_out, int out_size, void* d_ws, size_t ws_size,
                              hipStream_t stream)
{
  const float* x   = (const float*)d_in[0];
  const float* Wx0 = (const float*)d_in[1];
  const float* bx0 = (const float*)d_in[2];
  const float* Wh0 = (const float*)d_in[3];
  const float* Wx1 = (const float*)d_in[4];
  const float* bx1 = (const float*)d_in[5];
  const float* Wh1 = (const float*)d_in[6];
  const float* Wfc = (const float*)d_in[7];
  const float* bfc = (const float*)d_in[8];

  uint8_t* ws = (uint8_t*)d_ws;
  const size_t RINGB_FULL = (size_t)(T_ + 1) * SLOT_B;   // 65.7 MB per ring
  const size_t RINGB_CYC  = (size_t)D_ * SLOT_B;         // 1 MB per ring
  const size_t NEED_FULL  = 4096 + 2 * RINGB_FULL + (size_t)B_ * H_ * 4;

  uint32_t* prog0 = (uint32_t*)ws;              // FULL: 512 words; CYC: 128
  uint32_t* prog1 = (uint32_t*)(ws + 2048);

  if (ws_size >= NEED_FULL) {
    uint8_t* ring0 = ws + 4096;
    uint8_t* ring1 = ws + 4096 + RINGB_FULL;
    float* h1f = (float*)(ws + 4096 + 2 * RINGB_FULL);
    (void)hipMemsetAsync(ws, 0, 4096 + SLOT_B, stream);   // flags + ring0 slot0
    (void)hipMemsetAsync(ring1, 0, SLOT_B, stream);       // ring1 slot0
    hipLaunchKernelGGL(lstm_persist<true>, dim3(G0_ + G1_), dim3(NTHR_), 0, stream,
                       x, Wx0, bx0, Wh0, Wx1, bx1, Wh1,
                       prog0, prog1, ring0, ring1, h1f);
    hipLaunchKernelGGL(fc_out, dim3(1), dim3(512), 0, stream,
                       h1f, Wfc, bfc, (float*)d_out);
  } else {
    uint8_t* ring0 = ws + 4096;
    uint8_t* ring1 = ws + 4096 + RINGB_CYC;
    float* h1f = (float*)(ws + 4096 + 2 * RINGB_CYC);
    (void)hipMemsetAsync(ws, 0, 4096 + 2 * RINGB_CYC, stream);
    hipLaunchKernelGGL(lstm_persist<false>, dim3(G0_ + G1_), dim3(NTHR_), 0, stream,
                       x, Wx0, bx0, Wh0, Wx1, bx1, Wh1,
                       prog0, prog1, ring0, ring1, h1f);
    hipLaunchKernelGGL(fc_out, dim3(1), dim3(512), 0, stream,
                       h1f, Wfc, bfc, (float*)d_out);
  }
}